// Round 21
// baseline (197.836 us; speedup 1.0000x reference)
//
#include <hip/hip_runtime.h>
#include <hip/hip_bf16.h>
#include <cstdint>

typedef _Float16 half8 __attribute__((ext_vector_type(8)));
typedef float f32x4 __attribute__((ext_vector_type(4)));
typedef unsigned u32x4 __attribute__((ext_vector_type(4)));

__device__ __forceinline__ void gload16(const void* g, void* l) {
  __builtin_amdgcn_global_load_lds((__attribute__((address_space(1))) void*)(g),
                                   (__attribute__((address_space(3))) void*)(l), 16, 0, 0);
}

// ---------------- fused prep: x->f16 convert + 6 weight transposes + trig table ----------------
// blocks [0,4096):      conv of x, 8 floats/thread (2x float4 -> 1x half8)
// blocks [4096,13312):  32x32-tile transposes (verified body)
// blocks [13312,13824): trig table [2048 s][64 cos | 64 sin] fp32 (into vT region head)
__global__ __launch_bounds__(256) void prep(const float* __restrict__ x,
                                            _Float16* __restrict__ xb,
                                            const float* __restrict__ Wq_d,
                                            const float* __restrict__ Wkv_d,
                                            const float* __restrict__ Wq_u,
                                            const float* __restrict__ Wk_u,
                                            const float* __restrict__ Wv_u,
                                            const float* __restrict__ Wo,
                                            _Float16* __restrict__ wdT,
                                            _Float16* __restrict__ wuT,
                                            _Float16* __restrict__ woT,
                                            float* __restrict__ tab) {
  const int bid = (int)blockIdx.x;
  const int tid = threadIdx.x;
  if (bid < 4096) {
    int i = (bid * 256 + tid) * 8;
    float4 v0 = *reinterpret_cast<const float4*>(x + i);
    float4 v1 = *reinterpret_cast<const float4*>(x + i + 4);
    half8 o;
    o[0] = (_Float16)v0.x; o[1] = (_Float16)v0.y; o[2] = (_Float16)v0.z; o[3] = (_Float16)v0.w;
    o[4] = (_Float16)v1.x; o[5] = (_Float16)v1.y; o[6] = (_Float16)v1.z; o[7] = (_Float16)v1.w;
    *reinterpret_cast<half8*>(xb + i) = o;
    return;
  }
  if (bid >= 13312) {
    int idx = (bid - 13312) * 256 + tid;  // 0..131071 = 2048*64
    int s = idx >> 6, dp = idx & 63;
    float invf = exp2f(-(float)dp * (13.287712379549449f / 64.0f));
    float f = (float)s * invf;
    float sn, cs;
    sincosf(f, &sn, &cs);
    tab[s * 128 + dp] = cs;
    tab[s * 128 + 64 + dp] = sn;
    return;
  }
  int t = bid - 4096;
  const float* src;
  _Float16* dst;
  int R, C, gx, lb;
  if (t < 1024)      { src = Wq_d;  dst = wdT;             R = 2048; C = 512;  gx = 16; lb = t; }
  else if (t < 2048) { src = Wkv_d; dst = wdT + 1048576;   R = 2048; C = 512;  gx = 16; lb = t - 1024; }
  else if (t < 3072) { src = Wq_u;  dst = wuT;             R = 512;  C = 2048; gx = 64; lb = t - 2048; }
  else if (t < 4096) { src = Wk_u;  dst = wuT + 1048576;   R = 512;  C = 2048; gx = 64; lb = t - 3072; }
  else if (t < 5120) { src = Wv_u;  dst = wuT + 2097152;   R = 512;  C = 2048; gx = 64; lb = t - 4096; }
  else               { src = Wo;    dst = woT;             R = 2048; C = 2048; gx = 64; lb = t - 5120; }
  __shared__ float tile[32][33];
  int c0 = (lb % gx) * 32, r0 = (lb / gx) * 32;
  int xx = tid & 31, yy = tid >> 5;
#pragma unroll
  for (int j = 0; j < 4; ++j)
    tile[yy + j * 8][xx] = src[(long)(r0 + yy + j * 8) * C + c0 + xx];
  __syncthreads();
#pragma unroll
  for (int j = 0; j < 4; ++j)
    dst[(long)(c0 + yy + j * 8) * R + r0 + xx] = (_Float16)tile[xx][yy + j * 8];
}

// ---------------- GEMM: C[M][N] = A[M][K] * BT[N][K]^T ----------------
// 128x128 tile, BK=64, double-buffered global_load_lds staging, XCD swizzle.
// Wave->col mapping: col = (ni>>1)*64 + wn*32 + (ni&1)*16 + (lane&15)  [bijective]
// MODE: 0 = f16 store, 1 = f32 store, 2 = f16 store with fused RoPE.
template <int MODE>
__global__ __launch_bounds__(256) void gemm_bt(const _Float16* __restrict__ A, int lda,
                                               const _Float16* __restrict__ BT, int ldb,
                                               void* __restrict__ Cv, int ldc, int K,
                                               const float* __restrict__ tab) {
  __shared__ alignas(16) char As[2][128 * 128];
  __shared__ alignas(16) char Bs[2][128 * 128];
  const int tid = threadIdx.x;
  const int lane = tid & 63;
  const int wave = tid >> 6;
  const int wm = wave >> 1, wn = wave & 1;
  const int nwg = (int)(gridDim.x * gridDim.y);
  const int bid = (int)(blockIdx.y * gridDim.x + blockIdx.x);
  const int swz = (bid & 7) * (nwg >> 3) + (bid >> 3);
  const int m0 = (swz / (int)gridDim.x) * 128, n0 = (swz % (int)gridDim.x) * 128;
  f32x4 acc[4][4] = {};
  int srow[4], scs[4];
#pragma unroll
  for (int j = 0; j < 4; ++j) {
    int i = j * 256 + tid;
    srow[j] = i >> 3;
    scs[j] = (i & 7) ^ (srow[j] & 7);
  }
  auto stage = [&](int k0, int buf) {
#pragma unroll
    for (int j = 0; j < 4; ++j)
      gload16(A + (long)(m0 + srow[j]) * lda + k0 + scs[j] * 8, As[buf] + (j * 256 + tid) * 16);
#pragma unroll
    for (int j = 0; j < 4; ++j)
      gload16(BT + (long)(n0 + srow[j]) * ldb + k0 + scs[j] * 8, Bs[buf] + (j * 256 + tid) * 16);
  };

  stage(0, 0);
  __syncthreads();
  const int nk = K >> 6;
  for (int t = 0; t < nk; ++t) {
    const int buf = t & 1;
    if (t + 1 < nk) stage((t + 1) << 6, buf ^ 1);
#pragma unroll
    for (int kk = 0; kk < 2; ++kk) {
      half8 af[4], bf[4];
#pragma unroll
      for (int mi = 0; mi < 4; ++mi) {
        int row = wm * 64 + mi * 16 + (lane & 15);
        int b = (row * 128 + kk * 64 + ((lane >> 4) * 16)) ^ ((row & 7) << 4);
        af[mi] = *reinterpret_cast<const half8*>(As[buf] + b);
      }
#pragma unroll
      for (int ni = 0; ni < 4; ++ni) {
        int row = (ni >> 1) * 64 + wn * 32 + (ni & 1) * 16 + (lane & 15);
        int b = (row * 128 + kk * 64 + ((lane >> 4) * 16)) ^ ((row & 7) << 4);
        bf[ni] = *reinterpret_cast<const half8*>(Bs[buf] + b);
      }
#pragma unroll
      for (int mi = 0; mi < 4; ++mi)
#pragma unroll
        for (int ni = 0; ni < 4; ++ni)
          acc[mi][ni] =
              __builtin_amdgcn_mfma_f32_16x16x32_f16(af[mi], bf[ni], acc[mi][ni], 0, 0, 0);
    }
    __syncthreads();
  }
#pragma unroll
  for (int mi = 0; mi < 4; ++mi) {
    const int row = m0 + wm * 64 + mi * 16 + ((lane >> 4) << 2);
    if constexpr (MODE == 2) {
      _Float16* C16 = reinterpret_cast<_Float16*>(Cv);
#pragma unroll
      for (int ni = 0; ni < 2; ++ni) {
        int dp = wn * 32 + ni * 16 + (lane & 15);  // 0..63
        f32x4 va = acc[mi][ni], vb = acc[mi][ni + 2];
#pragma unroll
        for (int r = 0; r < 4; ++r) {
          int s = (row + r) & 2047;
          float cs = tab[s * 128 + dp], sn = tab[s * 128 + 64 + dp];
          float a = va[r], b2 = vb[r];
          C16[(long)(row + r) * ldc + n0 + dp] = (_Float16)(a * cs - b2 * sn);
          C16[(long)(row + r) * ldc + n0 + dp + 64] = (_Float16)(b2 * cs + a * sn);
        }
      }
    } else {
#pragma unroll
      for (int ni = 0; ni < 4; ++ni) {
        int col = n0 + (ni >> 1) * 64 + wn * 32 + (ni & 1) * 16 + (lane & 15);
        f32x4 v = acc[mi][ni];
#pragma unroll
        for (int r = 0; r < 4; ++r) {
          if constexpr (MODE == 1)
            reinterpret_cast<float*>(Cv)[(long)(row + r) * ldc + col] = v[r];
          else
            reinterpret_cast<_Float16*>(Cv)[(long)(row + r) * ldc + col] = (_Float16)v[r];
        }
      }
    }
  }
}

// ---------------- down-proj GEMM: 128x64 tile -> 512 blocks (2/CU) ----------------
// lat[4096][1024] = xb[4096][2048] @ wdT[1024][2048]^T.  Same 2-barrier loop and
// swizzle formulas as gemm_bt (formulas depend only on row&7); BN=64, acc[4][2].
__global__ __launch_bounds__(256) void gemm_down(const _Float16* __restrict__ A,
                                                 const _Float16* __restrict__ BT,
                                                 _Float16* __restrict__ C) {
  __shared__ alignas(16) char As[2][128 * 128];
  __shared__ alignas(16) char Bs[2][64 * 128];
  const int tid = threadIdx.x;
  const int lane = tid & 63;
  const int wave = tid >> 6;
  const int wm = wave >> 1, wn = wave & 1;
  const int bid = (int)(blockIdx.y * gridDim.x + blockIdx.x);  // grid (16,32) -> 512
  const int swz = (bid & 7) * 64 + (bid >> 3);
  const int m0 = (swz >> 4) * 128, n0 = (swz & 15) * 64;
  f32x4 acc[4][2] = {};
  int arow[4], acs[4];
#pragma unroll
  for (int j = 0; j < 4; ++j) {
    int i = j * 256 + tid;
    arow[j] = i >> 3;
    acs[j] = (i & 7) ^ (arow[j] & 7);
  }
  int brow[2], bcs[2];
#pragma unroll
  for (int j = 0; j < 2; ++j) {
    int i = j * 256 + tid;
    brow[j] = i >> 3;
    bcs[j] = (i & 7) ^ (brow[j] & 7);
  }
  auto stage = [&](int k0, int buf) {
#pragma unroll
    for (int j = 0; j < 4; ++j)
      gload16(A + (long)(m0 + arow[j]) * 2048 + k0 + acs[j] * 8, As[buf] + (j * 256 + tid) * 16);
#pragma unroll
    for (int j = 0; j < 2; ++j)
      gload16(BT + (long)(n0 + brow[j]) * 2048 + k0 + bcs[j] * 8, Bs[buf] + (j * 256 + tid) * 16);
  };

  stage(0, 0);
  __syncthreads();
  const int nk = 32;  // K = 2048
  for (int t = 0; t < nk; ++t) {
    const int buf = t & 1;
    if (t + 1 < nk) stage((t + 1) << 6, buf ^ 1);
#pragma unroll
    for (int kk = 0; kk < 2; ++kk) {
      half8 af[4], bf[2];
#pragma unroll
      for (int mi = 0; mi < 4; ++mi) {
        int row = wm * 64 + mi * 16 + (lane & 15);
        int b = (row * 128 + kk * 64 + ((lane >> 4) * 16)) ^ ((row & 7) << 4);
        af[mi] = *reinterpret_cast<const half8*>(As[buf] + b);
      }
#pragma unroll
      for (int ni = 0; ni < 2; ++ni) {
        int row = wn * 32 + ni * 16 + (lane & 15);
        int b = (row * 128 + kk * 64 + ((lane >> 4) * 16)) ^ ((row & 7) << 4);
        bf[ni] = *reinterpret_cast<const half8*>(Bs[buf] + b);
      }
#pragma unroll
      for (int mi = 0; mi < 4; ++mi)
#pragma unroll
        for (int ni = 0; ni < 2; ++ni)
          acc[mi][ni] =
              __builtin_amdgcn_mfma_f32_16x16x32_f16(af[mi], bf[ni], acc[mi][ni], 0, 0, 0);
    }
    __syncthreads();
  }
#pragma unroll
  for (int mi = 0; mi < 4; ++mi) {
    const int row = m0 + wm * 64 + mi * 16 + ((lane >> 4) << 2);
#pragma unroll
    for (int ni = 0; ni < 2; ++ni) {
      int col = n0 + wn * 32 + ni * 16 + (lane & 15);
      f32x4 v = acc[mi][ni];
#pragma unroll
      for (int r = 0; r < 4; ++r)
        C[(long)(row + r) * 1024 + col] = (_Float16)v[r];
    }
  }
}

// ---------------- merged q+k up-projection: 1024 blocks, SAME shape/MODE, 3 ptr selects ----------------
__global__ __launch_bounds__(256) void gemm_qk(const _Float16* __restrict__ lat,
                                               const _Float16* __restrict__ wuT,
                                               _Float16* __restrict__ qb,
                                               _Float16* __restrict__ kb,
                                               const float* __restrict__ tab) {
  const int bid0 = (int)blockIdx.x;   // 0..1023
  const int job = bid0 >> 9;          // 0=q, 1=k
  const int bid = bid0 & 511;
  const _Float16* A = lat + (job ? 512 : 0);
  const _Float16* BT = wuT + (job ? 1048576 : 0);
  _Float16* C16 = job ? kb : qb;
  __shared__ alignas(16) char As[2][128 * 128];
  __shared__ alignas(16) char Bs[2][128 * 128];
  const int tid = threadIdx.x;
  const int lane = tid & 63;
  const int wave = tid >> 6;
  const int wm = wave >> 1, wn = wave & 1;
  const int swz = (bid & 7) * 64 + (bid >> 3);
  const int m0 = (swz / 16) * 128, n0 = (swz % 16) * 128;
  f32x4 acc[4][4] = {};
  int srow[4], scs[4];
#pragma unroll
  for (int j = 0; j < 4; ++j) {
    int i = j * 256 + tid;
    srow[j] = i >> 3;
    scs[j] = (i & 7) ^ (srow[j] & 7);
  }
  auto stage = [&](int k0, int buf) {
#pragma unroll
    for (int j = 0; j < 4; ++j)
      gload16(A + (long)(m0 + srow[j]) * 1024 + k0 + scs[j] * 8, As[buf] + (j * 256 + tid) * 16);
#pragma unroll
    for (int j = 0; j < 4; ++j)
      gload16(BT + (long)(n0 + srow[j]) * 512 + k0 + scs[j] * 8, Bs[buf] + (j * 256 + tid) * 16);
  };

  stage(0, 0);
  __syncthreads();
  const int nk = 8;  // K=512
  for (int t = 0; t < nk; ++t) {
    const int buf = t & 1;
    if (t + 1 < nk) stage((t + 1) << 6, buf ^ 1);
#pragma unroll
    for (int kk = 0; kk < 2; ++kk) {
      half8 af[4], bf[4];
#pragma unroll
      for (int mi = 0; mi < 4; ++mi) {
        int row = wm * 64 + mi * 16 + (lane & 15);
        int b = (row * 128 + kk * 64 + ((lane >> 4) * 16)) ^ ((row & 7) << 4);
        af[mi] = *reinterpret_cast<const half8*>(As[buf] + b);
      }
#pragma unroll
      for (int ni = 0; ni < 4; ++ni) {
        int row = (ni >> 1) * 64 + wn * 32 + (ni & 1) * 16 + (lane & 15);
        int b = (row * 128 + kk * 64 + ((lane >> 4) * 16)) ^ ((row & 7) << 4);
        bf[ni] = *reinterpret_cast<const half8*>(Bs[buf] + b);
      }
#pragma unroll
      for (int mi = 0; mi < 4; ++mi)
#pragma unroll
        for (int ni = 0; ni < 4; ++ni)
          acc[mi][ni] =
              __builtin_amdgcn_mfma_f32_16x16x32_f16(af[mi], bf[ni], acc[mi][ni], 0, 0, 0);
    }
    __syncthreads();
  }
#pragma unroll
  for (int mi = 0; mi < 4; ++mi) {
    const int row = m0 + wm * 64 + mi * 16 + ((lane >> 4) << 2);
#pragma unroll
    for (int ni = 0; ni < 2; ++ni) {
      int dp = wn * 32 + ni * 16 + (lane & 15);  // 0..63
      f32x4 va = acc[mi][ni], vb = acc[mi][ni + 2];
#pragma unroll
      for (int r = 0; r < 4; ++r) {
        int s = (row + r) & 2047;
        float cs = tab[s * 128 + dp], sn = tab[s * 128 + 64 + dp];
        float a = va[r], b2 = vb[r];
        C16[(long)(row + r) * 2048 + n0 + dp] = (_Float16)(a * cs - b2 * sn);
        C16[(long)(row + r) * 2048 + n0 + dp + 64] = (_Float16)(b2 * cs + a * sn);
      }
    }
  }
}

// ---------------- fused causal flash attention (r20 kernel, verbatim) ----------------
// flat<256 (dispatched first): qt = 15-(s&7) (heavy); flat>=256: qt = s&7 (light)
// -> every CU's two blocks total 34 tile-units; XCD clustering hb = xcd + 8*(s>>3).
// Softmax: broadcast-aown rescale + deferred l-sum (reduced once in epilogue).
__global__ __launch_bounds__(256, 2) void attn_fused(const _Float16* __restrict__ Q,
                                                     const _Float16* __restrict__ Kr,
                                                     const _Float16* __restrict__ VT,
                                                     _Float16* __restrict__ O) {
  __shared__ alignas(16) char Ks[2][64 * 256];    // [key][chunk^(key&7)]
  __shared__ alignas(16) char Vs[2][128 * 128];   // [d][chunk^(d&7)] of VT tile
  const int tid = threadIdx.x, lane = tid & 63, wave = tid >> 6;
  const int g = lane >> 4;
  const int flat = (int)(blockIdx.x + 16 * blockIdx.y + 256 * blockIdx.z);  // 0..511
  const int round = flat >> 8;
  const int r_ = flat & 255;
  const int xcd = r_ & 7;
  const int s_ = r_ >> 3;
  const int hb = xcd + 8 * (s_ >> 3);
  const int qt = round ? (s_ & 7) : 15 - (s_ & 7);
  const int h = hb & 15, b = hb >> 4;
  const long sbase = (long)b * 2048;
  const int q0 = qt * 128;
  const int colbase = h * 128;
  const int qa_own = q0 + wave * 32 + (lane & 15);
  const int qb_own = qa_own + 16;

  half8 qfa[4], qfb[4];
  {
    const _Float16 hs = (_Float16)0.08838834764831845f;
    const _Float16* qpa = Q + (sbase + qa_own) * 2048 + colbase + g * 8;
    const _Float16* qpb = Q + (sbase + qb_own) * 2048 + colbase + g * 8;
#pragma unroll
    for (int c = 0; c < 4; ++c) {
      qfa[c] = (*reinterpret_cast<const half8*>(qpa + c * 32)) * hs;
      qfb[c] = (*reinterpret_cast<const half8*>(qpb + c * 32)) * hs;
    }
  }
  f32x4 oa[8] = {}, ob[8] = {};
  float ma = -INFINITY, la = 0.f, mb = -INFINITY, lb = 0.f;  // la/lb: per-lane PARTIAL sums
  const int nt = 2 * qt + 2;

  int k_kr[4], k_cs[4], v_vr[4], v_cs[4];
#pragma unroll
  for (int j = 0; j < 4; ++j) {
    int ci = j * 256 + tid;
    k_kr[j] = ci >> 4;
    k_cs[j] = (ci & 15) ^ (k_kr[j] & 7);
    v_vr[j] = ci >> 3;
    v_cs[j] = (ci & 7) ^ (v_vr[j] & 7);
  }
  auto stage = [&](int k0, int buf) {
#pragma unroll
    for (int j = 0; j < 4; ++j)
      gload16(Kr + (sbase + k0 + k_kr[j]) * 2048 + colbase + k_cs[j] * 8,
              Ks[buf] + (j * 256 + tid) * 16);
#pragma unroll
    for (int j = 0; j < 4; ++j)
      gload16(VT + (long)(colbase + v_vr[j]) * 4096 + sbase + k0 + v_cs[j] * 8,
              Vs[buf] + (j * 256 + tid) * 16);
  };

  stage(0, 0);
  __syncthreads();

  for (int t = 0; t < nt; ++t) {
    const int cur = t & 1;
    const int k0 = t * 64;
    if (t + 1 < nt) stage(k0 + 64, cur ^ 1);

    const bool active = !(t == nt - 1 && wave < 2);
    if (active) {
      f32x4 sa[4] = {}, sb[4] = {};
      __builtin_amdgcn_s_setprio(1);
#pragma unroll
      for (int n = 0; n < 4; ++n) {
        int key = n * 16 + (lane & 15);
#pragma unroll
        for (int c = 0; c < 4; ++c) {
          half8 kf = *reinterpret_cast<const half8*>(
              Ks[cur] + key * 256 + (((c * 4 + g) ^ (key & 7)) * 16));
          sa[n] = __builtin_amdgcn_mfma_f32_16x16x32_f16(kf, qfa[c], sa[n], 0, 0, 0);
          sb[n] = __builtin_amdgcn_mfma_f32_16x16x32_f16(kf, qfb[c], sb[n], 0, 0, 0);
        }
      }
      __builtin_amdgcn_s_setprio(0);

      if (t >= nt - 2) {
        int kba = k0 + g * 4 - qa_own;
        int kbb = kba - 16;
#pragma unroll
        for (int n = 0; n < 4; ++n)
#pragma unroll
          for (int r = 0; r < 4; ++r) {
            if (kba + n * 16 + r > 0) sa[n][r] = -INFINITY;
            if (kbb + n * 16 + r > 0) sb[n][r] = -INFINITY;
          }
      }

      float mxa = fmaxf(fmaxf(fmaxf(sa[0][0], sa[0][1]), fmaxf(sa[0][2], sa[0][3])),
                        fmaxf(fmaxf(sa[1][0], sa[1][1]), fmaxf(sa[1][2], sa[1][3])));
      mxa = fmaxf(mxa, fmaxf(fmaxf(fmaxf(sa[2][0], sa[2][1]), fmaxf(sa[2][2], sa[2][3])),
                             fmaxf(fmaxf(sa[3][0], sa[3][1]), fmaxf(sa[3][2], sa[3][3]))));
      float mxb = fmaxf(fmaxf(fmaxf(sb[0][0], sb[0][1]), fmaxf(sb[0][2], sb[0][3])),
                        fmaxf(fmaxf(sb[1][0], sb[1][1]), fmaxf(sb[1][2], sb[1][3])));
      mxb = fmaxf(mxb, fmaxf(fmaxf(fmaxf(sb[2][0], sb[2][1]), fmaxf(sb[2][2], sb[2][3])),
                             fmaxf(fmaxf(sb[3][0], sb[3][1]), fmaxf(sb[3][2], sb[3][3]))));
      mxa = fmaxf(mxa, __shfl_xor(mxa, 16));
      mxa = fmaxf(mxa, __shfl_xor(mxa, 32));
      mxb = fmaxf(mxb, __shfl_xor(mxb, 16));
      mxb = fmaxf(mxb, __shfl_xor(mxb, 32));

      bool need = (mxa > ma + 8.f) || (mxb > mb + 8.f);
      if (__any(need)) {
        float mna = fmaxf(ma, mxa), mnb = fmaxf(mb, mxb);
        float aown = __expf(ma - mna), bown = __expf(mb - mnb);
        la *= aown;
        lb *= bown;
        ma = mna;
        mb = mnb;
        float alfa[4], alfb[4];
#pragma unroll
        for (int r = 0; r < 4; ++r) {
          alfa[r] = __shfl(aown, (lane & 48) | (g * 4 + r));
          alfb[r] = __shfl(bown, (lane & 48) | (g * 4 + r));
        }
#pragma unroll
        for (int n = 0; n < 8; ++n) {
          f32x4 ta = oa[n], tb = ob[n];
          ta[0] *= alfa[0]; ta[1] *= alfa[1]; ta[2] *= alfa[2]; ta[3] *= alfa[3];
          tb[0] *= alfb[0]; tb[1] *= alfb[1]; tb[2] *= alfb[2]; tb[3] *= alfb[3];
          oa[n] = ta; ob[n] = tb;
        }
      }

      float pea[4][4], peb[4][4];
#pragma unroll
      for (int n = 0; n < 4; ++n)
#pragma unroll
        for (int r = 0; r < 4; ++r) {
          pea[n][r] = __expf(sa[n][r] - ma);
          peb[n][r] = __expf(sb[n][r] - mb);
        }
      {
        float lsa = 0.f, lsb = 0.f;
#pragma unroll
        for (int n = 0; n < 4; ++n)
#pragma unroll
          for (int r = 0; r < 4; ++r) { lsa += pea[n][r]; lsb += peb[n][r]; }
        la += lsa;
        lb += lsb;
      }

      half8 paa[2], pab[2];
      {
        unsigned loa[4], hia[4], lob[4], hib[4];
#pragma unroll
        for (int n = 0; n < 4; ++n) {
          loa[n] = __builtin_bit_cast(unsigned, __builtin_amdgcn_cvt_pkrtz(pea[n][0], pea[n][1]));
          hia[n] = __builtin_bit_cast(unsigned, __builtin_amdgcn_cvt_pkrtz(pea[n][2], pea[n][3]));
          lob[n] = __builtin_bit_cast(unsigned, __builtin_amdgcn_cvt_pkrtz(peb[n][0], peb[n][1]));
          hib[n] = __builtin_bit_cast(unsigned, __builtin_amdgcn_cvt_pkrtz(peb[n][2], peb[n][3]));
        }
#pragma unroll
        for (int ks = 0; ks < 2; ++ks) {
          unsigned al = loa[ks * 2], bl = loa[ks * 2 + 1];
          unsigned ah = hia[ks * 2], bh = hia[ks * 2 + 1];
          asm("v_permlane32_swap_b32 %0, %1" : "+v"(al), "+v"(bl));
          asm("v_permlane16_swap_b32 %0, %1" : "+v"(al), "+v"(bl));
          asm("v_permlane32_swap_b32 %0, %1" : "+v"(ah), "+v"(bh));
          asm("v_permlane16_swap_b32 %0, %1" : "+v"(ah), "+v"(bh));
          u32x4 w; w[0] = al; w[1] = ah; w[2] = bl; w[3] = bh;
          paa[ks] = __builtin_bit_cast(half8, w);
          unsigned al2 = lob[ks * 2], bl2 = lob[ks * 2 + 1];
          unsigned ah2 = hib[ks * 2], bh2 = hib[ks * 2 + 1];
          asm("v_permlane32_swap_b32 %0, %1" : "+v"(al2), "+v"(bl2));
          asm("v_permlane16_swap_b32 %0, %1" : "+v"(al2), "+v"(bl2));
          asm("v_permlane32_swap_b32 %0, %1" : "+v"(ah2), "+v"(bh2));
          asm("v_permlane16_swap_b32 %0, %1" : "+v"(ah2), "+v"(bh2));
          u32x4 w2; w2[0] = al2; w2[1] = ah2; w2[2] = bl2; w2[3] = bh2;
          pab[ks] = __builtin_bit_cast(half8, w2);
        }
      }

      __builtin_amdgcn_s_setprio(1);
#pragma unroll
      for (int n = 0; n < 8; ++n) {
        int d = n * 16 + (lane & 15);
#pragma unroll
        for (int ks = 0; ks < 2; ++ks) {
          half8 vf = *reinterpret_cast<const half8*>(
              Vs[cur] + d * 128 + (((ks * 4 + g) ^ (d & 7)) * 16));
          oa[n] = __builtin_amdgcn_mfma_f32_16x16x32_f16(paa[ks], vf, oa[n], 0, 0, 0);
          ob[n] = __builtin_amdgcn_mfma_f32_16x16x32_f16(pab[ks], vf, ob[n], 0, 0, 0);
        }
      }
      __builtin_amdgcn_s_setprio(0);
    }
    __syncthreads();
  }

  // epilogue: collapse deferred l partials, then rcp + multiply
  la += __shfl_xor(la, 16);
  la += __shfl_xor(la, 32);
  lb += __shfl_xor(lb, 16);
  lb += __shfl_xor(lb, 32);
  float lra[4], lrb[4];
#pragma unroll
  for (int r = 0; r < 4; ++r) {
    lra[r] = __builtin_amdgcn_rcpf(__shfl(la, (lane & 48) | (g * 4 + r)));
    lrb[r] = __builtin_amdgcn_rcpf(__shfl(lb, (lane & 48) | (g * 4 + r)));
  }
#pragma unroll
  for (int n = 0; n < 8; ++n) {
    int d = colbase + n * 16 + (lane & 15);
#pragma unroll
    for (int r = 0; r < 4; ++r) {
      int rowa = q0 + wave * 32 + (g << 2) + r;
      O[(sbase + rowa) * 2048 + d] = (_Float16)(oa[n][r] * lra[r]);
      O[(sbase + rowa + 16) * 2048 + d] = (_Float16)(ob[n][r] * lrb[r]);
    }
  }
}

extern "C" void kernel_launch(void* const* d_in, const int* in_sizes, int n_in,
                              void* d_out, int out_size, void* d_ws, size_t ws_size,
                              hipStream_t stream) {
  const float* x     = (const float*)d_in[0];
  const float* Wq_d  = (const float*)d_in[1];
  const float* Wkv_d = (const float*)d_in[2];
  const float* Wq_u  = (const float*)d_in[3];
  const float* Wk_u  = (const float*)d_in[4];
  const float* Wv_u  = (const float*)d_in[5];
  const float* Wo    = (const float*)d_in[6];
  char* ws = (char*)d_ws;
  _Float16* xb  = (_Float16*)(ws);              // [4096][2048] (reused as ao)
  _Float16* wdT = (_Float16*)(ws + 16777216);   // [1024][2048]
  _Float16* wuT = (_Float16*)(ws + 20971520);   // 3x [2048][512]
  _Float16* woT = (_Float16*)(ws + 27262976);   // [2048][2048]
  _Float16* lat = (_Float16*)(ws + 35651584);   // [4096][1024]
  _Float16* qb  = (_Float16*)(ws + 44040192);   // [4096][2048]
  _Float16* kb  = (_Float16*)(ws + 60817408);   // [4096][2048]
  _Float16* vT  = (_Float16*)(ws + 77594624);   // [2048 d][4096 s]
  float*    tab = (float*)(ws + 77594624);      // 1 MB trig table, head of vT region:
                                                // written by prep, read by gemm_qk,
                                                // overwritten later by the v-GEMM (after qk).
  _Float16* ao  = xb;

  // fused conv (vectorized) + all weight transposes + trig table (one dispatch)
  prep<<<13824, 256, 0, stream>>>(x, xb, Wq_d, Wkv_d, Wq_u, Wk_u, Wv_u, Wo, wdT, wuT, woT, tab);

  // lat = x @ [Wq_d | Wkv_d]   (128x64-tile variant: 512 blocks, 2/CU)
  gemm_down<<<dim3(16, 32), 256, 0, stream>>>(xb, wdT, lat);

  // q = RoPE(lat_q @ Wq_u) ; k = RoPE(lat_kv @ Wk_u)  -- merged, one dispatch (reads tab)
  gemm_qk<<<1024, 256, 0, stream>>>(lat, wuT, qb, kb, tab);
  // vT[d][s] = Wv_u^T @ lat_kv^T  (overwrites the tab region — tab is dead now)
  gemm_bt<0><<<dim3(32, 16), 256, 0, stream>>>(wuT + 2 * 2048 * 512, 512, lat + 512, 1024, vT, 4096, 512, nullptr);

  attn_fused<<<dim3(16, 16, 2), 256, 0, stream>>>(qb, kb, vT, ao);

  gemm_bt<1><<<dim3(16, 32), 256, 0, stream>>>(ao, 2048, woT, 2048, d_out, 2048, 2048, nullptr);
}

// Round 22
// 184.365 us; speedup vs baseline: 1.0731x; 1.0731x over previous
//
#include <hip/hip_runtime.h>
#include <hip/hip_bf16.h>
#include <cstdint>

typedef _Float16 half8 __attribute__((ext_vector_type(8)));
typedef float f32x4 __attribute__((ext_vector_type(4)));
typedef unsigned u32x4 __attribute__((ext_vector_type(4)));

__device__ __forceinline__ void gload16(const void* g, void* l) {
  __builtin_amdgcn_global_load_lds((__attribute__((address_space(1))) void*)(g),
                                   (__attribute__((address_space(3))) void*)(l), 16, 0, 0);
}

// ---------------- fused prep: x->f16 convert + 6 weight transposes + trig table ----------------
// blocks [0,4096):      conv of x, 8 floats/thread (2x float4 -> 1x half8)
// blocks [4096,13312):  32x32-tile transposes (verified body)
// blocks [13312,13824): trig table [2048 s][64 cos | 64 sin] fp32 (into vT region head)
__global__ __launch_bounds__(256) void prep(const float* __restrict__ x,
                                            _Float16* __restrict__ xb,
                                            const float* __restrict__ Wq_d,
                                            const float* __restrict__ Wkv_d,
                                            const float* __restrict__ Wq_u,
                                            const float* __restrict__ Wk_u,
                                            const float* __restrict__ Wv_u,
                                            const float* __restrict__ Wo,
                                            _Float16* __restrict__ wdT,
                                            _Float16* __restrict__ wuT,
                                            _Float16* __restrict__ woT,
                                            float* __restrict__ tab) {
  const int bid = (int)blockIdx.x;
  const int tid = threadIdx.x;
  if (bid < 4096) {
    int i = (bid * 256 + tid) * 8;
    float4 v0 = *reinterpret_cast<const float4*>(x + i);
    float4 v1 = *reinterpret_cast<const float4*>(x + i + 4);
    half8 o;
    o[0] = (_Float16)v0.x; o[1] = (_Float16)v0.y; o[2] = (_Float16)v0.z; o[3] = (_Float16)v0.w;
    o[4] = (_Float16)v1.x; o[5] = (_Float16)v1.y; o[6] = (_Float16)v1.z; o[7] = (_Float16)v1.w;
    *reinterpret_cast<half8*>(xb + i) = o;
    return;
  }
  if (bid >= 13312) {
    int idx = (bid - 13312) * 256 + tid;  // 0..131071 = 2048*64
    int s = idx >> 6, dp = idx & 63;
    float invf = exp2f(-(float)dp * (13.287712379549449f / 64.0f));
    float f = (float)s * invf;
    float sn, cs;
    sincosf(f, &sn, &cs);
    tab[s * 128 + dp] = cs;
    tab[s * 128 + 64 + dp] = sn;
    return;
  }
  int t = bid - 4096;
  const float* src;
  _Float16* dst;
  int R, C, gx, lb;
  if (t < 1024)      { src = Wq_d;  dst = wdT;             R = 2048; C = 512;  gx = 16; lb = t; }
  else if (t < 2048) { src = Wkv_d; dst = wdT + 1048576;   R = 2048; C = 512;  gx = 16; lb = t - 1024; }
  else if (t < 3072) { src = Wq_u;  dst = wuT;             R = 512;  C = 2048; gx = 64; lb = t - 2048; }
  else if (t < 4096) { src = Wk_u;  dst = wuT + 1048576;   R = 512;  C = 2048; gx = 64; lb = t - 3072; }
  else if (t < 5120) { src = Wv_u;  dst = wuT + 2097152;   R = 512;  C = 2048; gx = 64; lb = t - 4096; }
  else               { src = Wo;    dst = woT;             R = 2048; C = 2048; gx = 64; lb = t - 5120; }
  __shared__ float tile[32][33];
  int c0 = (lb % gx) * 32, r0 = (lb / gx) * 32;
  int xx = tid & 31, yy = tid >> 5;
#pragma unroll
  for (int j = 0; j < 4; ++j)
    tile[yy + j * 8][xx] = src[(long)(r0 + yy + j * 8) * C + c0 + xx];
  __syncthreads();
#pragma unroll
  for (int j = 0; j < 4; ++j)
    dst[(long)(c0 + yy + j * 8) * R + r0 + xx] = (_Float16)tile[xx][yy + j * 8];
}

// ---------------- GEMM: C[M][N] = A[M][K] * BT[N][K]^T ----------------
// 128x128 tile, BK=64, double-buffered global_load_lds staging, XCD swizzle.
// Wave->col mapping: col = (ni>>1)*64 + wn*32 + (ni&1)*16 + (lane&15)  [bijective]
// MODE: 0 = f16 store, 1 = f32 store, 2 = f16 store with fused RoPE.
template <int MODE>
__global__ __launch_bounds__(256) void gemm_bt(const _Float16* __restrict__ A, int lda,
                                               const _Float16* __restrict__ BT, int ldb,
                                               void* __restrict__ Cv, int ldc, int K,
                                               const float* __restrict__ tab) {
  __shared__ alignas(16) char As[2][128 * 128];
  __shared__ alignas(16) char Bs[2][128 * 128];
  const int tid = threadIdx.x;
  const int lane = tid & 63;
  const int wave = tid >> 6;
  const int wm = wave >> 1, wn = wave & 1;
  const int nwg = (int)(gridDim.x * gridDim.y);
  const int bid = (int)(blockIdx.y * gridDim.x + blockIdx.x);
  const int swz = (bid & 7) * (nwg >> 3) + (bid >> 3);
  const int m0 = (swz / (int)gridDim.x) * 128, n0 = (swz % (int)gridDim.x) * 128;
  f32x4 acc[4][4] = {};
  int srow[4], scs[4];
#pragma unroll
  for (int j = 0; j < 4; ++j) {
    int i = j * 256 + tid;
    srow[j] = i >> 3;
    scs[j] = (i & 7) ^ (srow[j] & 7);
  }
  auto stage = [&](int k0, int buf) {
#pragma unroll
    for (int j = 0; j < 4; ++j)
      gload16(A + (long)(m0 + srow[j]) * lda + k0 + scs[j] * 8, As[buf] + (j * 256 + tid) * 16);
#pragma unroll
    for (int j = 0; j < 4; ++j)
      gload16(BT + (long)(n0 + srow[j]) * ldb + k0 + scs[j] * 8, Bs[buf] + (j * 256 + tid) * 16);
  };

  stage(0, 0);
  __syncthreads();
  const int nk = K >> 6;
  for (int t = 0; t < nk; ++t) {
    const int buf = t & 1;
    if (t + 1 < nk) stage((t + 1) << 6, buf ^ 1);
#pragma unroll
    for (int kk = 0; kk < 2; ++kk) {
      half8 af[4], bf[4];
#pragma unroll
      for (int mi = 0; mi < 4; ++mi) {
        int row = wm * 64 + mi * 16 + (lane & 15);
        int b = (row * 128 + kk * 64 + ((lane >> 4) * 16)) ^ ((row & 7) << 4);
        af[mi] = *reinterpret_cast<const half8*>(As[buf] + b);
      }
#pragma unroll
      for (int ni = 0; ni < 4; ++ni) {
        int row = (ni >> 1) * 64 + wn * 32 + (ni & 1) * 16 + (lane & 15);
        int b = (row * 128 + kk * 64 + ((lane >> 4) * 16)) ^ ((row & 7) << 4);
        bf[ni] = *reinterpret_cast<const half8*>(Bs[buf] + b);
      }
#pragma unroll
      for (int mi = 0; mi < 4; ++mi)
#pragma unroll
        for (int ni = 0; ni < 4; ++ni)
          acc[mi][ni] =
              __builtin_amdgcn_mfma_f32_16x16x32_f16(af[mi], bf[ni], acc[mi][ni], 0, 0, 0);
    }
    __syncthreads();
  }
#pragma unroll
  for (int mi = 0; mi < 4; ++mi) {
    const int row = m0 + wm * 64 + mi * 16 + ((lane >> 4) << 2);
    if constexpr (MODE == 2) {
      _Float16* C16 = reinterpret_cast<_Float16*>(Cv);
#pragma unroll
      for (int ni = 0; ni < 2; ++ni) {
        int dp = wn * 32 + ni * 16 + (lane & 15);  // 0..63
        f32x4 va = acc[mi][ni], vb = acc[mi][ni + 2];
#pragma unroll
        for (int r = 0; r < 4; ++r) {
          int s = (row + r) & 2047;
          float cs = tab[s * 128 + dp], sn = tab[s * 128 + 64 + dp];
          float a = va[r], b2 = vb[r];
          C16[(long)(row + r) * ldc + n0 + dp] = (_Float16)(a * cs - b2 * sn);
          C16[(long)(row + r) * ldc + n0 + dp + 64] = (_Float16)(b2 * cs + a * sn);
        }
      }
    } else {
#pragma unroll
      for (int ni = 0; ni < 4; ++ni) {
        int col = n0 + (ni >> 1) * 64 + wn * 32 + (ni & 1) * 16 + (lane & 15);
        f32x4 v = acc[mi][ni];
#pragma unroll
        for (int r = 0; r < 4; ++r) {
          if constexpr (MODE == 1)
            reinterpret_cast<float*>(Cv)[(long)(row + r) * ldc + col] = v[r];
          else
            reinterpret_cast<_Float16*>(Cv)[(long)(row + r) * ldc + col] = (_Float16)v[r];
        }
      }
    }
  }
}

// ---------------- merged q+k up-projection: 1024 blocks, SAME shape/MODE, 3 ptr selects ----------------
__global__ __launch_bounds__(256) void gemm_qk(const _Float16* __restrict__ lat,
                                               const _Float16* __restrict__ wuT,
                                               _Float16* __restrict__ qb,
                                               _Float16* __restrict__ kb,
                                               const float* __restrict__ tab) {
  const int bid0 = (int)blockIdx.x;   // 0..1023
  const int job = bid0 >> 9;          // 0=q, 1=k
  const int bid = bid0 & 511;
  const _Float16* A = lat + (job ? 512 : 0);
  const _Float16* BT = wuT + (job ? 1048576 : 0);
  _Float16* C16 = job ? kb : qb;
  __shared__ alignas(16) char As[2][128 * 128];
  __shared__ alignas(16) char Bs[2][128 * 128];
  const int tid = threadIdx.x;
  const int lane = tid & 63;
  const int wave = tid >> 6;
  const int wm = wave >> 1, wn = wave & 1;
  const int swz = (bid & 7) * 64 + (bid >> 3);
  const int m0 = (swz / 16) * 128, n0 = (swz % 16) * 128;
  f32x4 acc[4][4] = {};
  int srow[4], scs[4];
#pragma unroll
  for (int j = 0; j < 4; ++j) {
    int i = j * 256 + tid;
    srow[j] = i >> 3;
    scs[j] = (i & 7) ^ (srow[j] & 7);
  }
  auto stage = [&](int k0, int buf) {
#pragma unroll
    for (int j = 0; j < 4; ++j)
      gload16(A + (long)(m0 + srow[j]) * 1024 + k0 + scs[j] * 8, As[buf] + (j * 256 + tid) * 16);
#pragma unroll
    for (int j = 0; j < 4; ++j)
      gload16(BT + (long)(n0 + srow[j]) * 512 + k0 + scs[j] * 8, Bs[buf] + (j * 256 + tid) * 16);
  };

  stage(0, 0);
  __syncthreads();
  const int nk = 8;  // K=512
  for (int t = 0; t < nk; ++t) {
    const int buf = t & 1;
    if (t + 1 < nk) stage((t + 1) << 6, buf ^ 1);
#pragma unroll
    for (int kk = 0; kk < 2; ++kk) {
      half8 af[4], bf[4];
#pragma unroll
      for (int mi = 0; mi < 4; ++mi) {
        int row = wm * 64 + mi * 16 + (lane & 15);
        int b = (row * 128 + kk * 64 + ((lane >> 4) * 16)) ^ ((row & 7) << 4);
        af[mi] = *reinterpret_cast<const half8*>(As[buf] + b);
      }
#pragma unroll
      for (int ni = 0; ni < 4; ++ni) {
        int row = (ni >> 1) * 64 + wn * 32 + (ni & 1) * 16 + (lane & 15);
        int b = (row * 128 + kk * 64 + ((lane >> 4) * 16)) ^ ((row & 7) << 4);
        bf[ni] = *reinterpret_cast<const half8*>(Bs[buf] + b);
      }
#pragma unroll
      for (int mi = 0; mi < 4; ++mi)
#pragma unroll
        for (int ni = 0; ni < 4; ++ni)
          acc[mi][ni] =
              __builtin_amdgcn_mfma_f32_16x16x32_f16(af[mi], bf[ni], acc[mi][ni], 0, 0, 0);
    }
    __syncthreads();
  }
#pragma unroll
  for (int mi = 0; mi < 4; ++mi) {
    const int row = m0 + wm * 64 + mi * 16 + ((lane >> 4) << 2);
#pragma unroll
    for (int ni = 0; ni < 2; ++ni) {
      int dp = wn * 32 + ni * 16 + (lane & 15);  // 0..63
      f32x4 va = acc[mi][ni], vb = acc[mi][ni + 2];
#pragma unroll
      for (int r = 0; r < 4; ++r) {
        int s = (row + r) & 2047;
        float cs = tab[s * 128 + dp], sn = tab[s * 128 + 64 + dp];
        float a = va[r], b2 = vb[r];
        C16[(long)(row + r) * 2048 + n0 + dp] = (_Float16)(a * cs - b2 * sn);
        C16[(long)(row + r) * 2048 + n0 + dp + 64] = (_Float16)(b2 * cs + a * sn);
      }
    }
  }
}

// ---------------- fused causal flash attention (r20 kernel, verbatim) ----------------
// flat<256 (dispatched first): qt = 15-(s&7) (heavy); flat>=256: qt = s&7 (light)
// -> every CU's two blocks total 34 tile-units; XCD clustering hb = xcd + 8*(s>>3).
// Softmax: broadcast-aown rescale + deferred l-sum (reduced once in epilogue).
__global__ __launch_bounds__(256, 2) void attn_fused(const _Float16* __restrict__ Q,
                                                     const _Float16* __restrict__ Kr,
                                                     const _Float16* __restrict__ VT,
                                                     _Float16* __restrict__ O) {
  __shared__ alignas(16) char Ks[2][64 * 256];    // [key][chunk^(key&7)]
  __shared__ alignas(16) char Vs[2][128 * 128];   // [d][chunk^(d&7)] of VT tile
  const int tid = threadIdx.x, lane = tid & 63, wave = tid >> 6;
  const int g = lane >> 4;
  const int flat = (int)(blockIdx.x + 16 * blockIdx.y + 256 * blockIdx.z);  // 0..511
  const int round = flat >> 8;
  const int r_ = flat & 255;
  const int xcd = r_ & 7;
  const int s_ = r_ >> 3;
  const int hb = xcd + 8 * (s_ >> 3);
  const int qt = round ? (s_ & 7) : 15 - (s_ & 7);
  const int h = hb & 15, b = hb >> 4;
  const long sbase = (long)b * 2048;
  const int q0 = qt * 128;
  const int colbase = h * 128;
  const int qa_own = q0 + wave * 32 + (lane & 15);
  const int qb_own = qa_own + 16;

  half8 qfa[4], qfb[4];
  {
    const _Float16 hs = (_Float16)0.08838834764831845f;
    const _Float16* qpa = Q + (sbase + qa_own) * 2048 + colbase + g * 8;
    const _Float16* qpb = Q + (sbase + qb_own) * 2048 + colbase + g * 8;
#pragma unroll
    for (int c = 0; c < 4; ++c) {
      qfa[c] = (*reinterpret_cast<const half8*>(qpa + c * 32)) * hs;
      qfb[c] = (*reinterpret_cast<const half8*>(qpb + c * 32)) * hs;
    }
  }
  f32x4 oa[8] = {}, ob[8] = {};
  float ma = -INFINITY, la = 0.f, mb = -INFINITY, lb = 0.f;  // la/lb: per-lane PARTIAL sums
  const int nt = 2 * qt + 2;

  int k_kr[4], k_cs[4], v_vr[4], v_cs[4];
#pragma unroll
  for (int j = 0; j < 4; ++j) {
    int ci = j * 256 + tid;
    k_kr[j] = ci >> 4;
    k_cs[j] = (ci & 15) ^ (k_kr[j] & 7);
    v_vr[j] = ci >> 3;
    v_cs[j] = (ci & 7) ^ (v_vr[j] & 7);
  }
  auto stage = [&](int k0, int buf) {
#pragma unroll
    for (int j = 0; j < 4; ++j)
      gload16(Kr + (sbase + k0 + k_kr[j]) * 2048 + colbase + k_cs[j] * 8,
              Ks[buf] + (j * 256 + tid) * 16);
#pragma unroll
    for (int j = 0; j < 4; ++j)
      gload16(VT + (long)(colbase + v_vr[j]) * 4096 + sbase + k0 + v_cs[j] * 8,
              Vs[buf] + (j * 256 + tid) * 16);
  };

  stage(0, 0);
  __syncthreads();

  for (int t = 0; t < nt; ++t) {
    const int cur = t & 1;
    const int k0 = t * 64;
    if (t + 1 < nt) stage(k0 + 64, cur ^ 1);

    const bool active = !(t == nt - 1 && wave < 2);
    if (active) {
      f32x4 sa[4] = {}, sb[4] = {};
      __builtin_amdgcn_s_setprio(1);
#pragma unroll
      for (int n = 0; n < 4; ++n) {
        int key = n * 16 + (lane & 15);
#pragma unroll
        for (int c = 0; c < 4; ++c) {
          half8 kf = *reinterpret_cast<const half8*>(
              Ks[cur] + key * 256 + (((c * 4 + g) ^ (key & 7)) * 16));
          sa[n] = __builtin_amdgcn_mfma_f32_16x16x32_f16(kf, qfa[c], sa[n], 0, 0, 0);
          sb[n] = __builtin_amdgcn_mfma_f32_16x16x32_f16(kf, qfb[c], sb[n], 0, 0, 0);
        }
      }
      __builtin_amdgcn_s_setprio(0);

      if (t >= nt - 2) {
        int kba = k0 + g * 4 - qa_own;
        int kbb = kba - 16;
#pragma unroll
        for (int n = 0; n < 4; ++n)
#pragma unroll
          for (int r = 0; r < 4; ++r) {
            if (kba + n * 16 + r > 0) sa[n][r] = -INFINITY;
            if (kbb + n * 16 + r > 0) sb[n][r] = -INFINITY;
          }
      }

      float mxa = fmaxf(fmaxf(fmaxf(sa[0][0], sa[0][1]), fmaxf(sa[0][2], sa[0][3])),
                        fmaxf(fmaxf(sa[1][0], sa[1][1]), fmaxf(sa[1][2], sa[1][3])));
      mxa = fmaxf(mxa, fmaxf(fmaxf(fmaxf(sa[2][0], sa[2][1]), fmaxf(sa[2][2], sa[2][3])),
                             fmaxf(fmaxf(sa[3][0], sa[3][1]), fmaxf(sa[3][2], sa[3][3]))));
      float mxb = fmaxf(fmaxf(fmaxf(sb[0][0], sb[0][1]), fmaxf(sb[0][2], sb[0][3])),
                        fmaxf(fmaxf(sb[1][0], sb[1][1]), fmaxf(sb[1][2], sb[1][3])));
      mxb = fmaxf(mxb, fmaxf(fmaxf(fmaxf(sb[2][0], sb[2][1]), fmaxf(sb[2][2], sb[2][3])),
                             fmaxf(fmaxf(sb[3][0], sb[3][1]), fmaxf(sb[3][2], sb[3][3]))));
      mxa = fmaxf(mxa, __shfl_xor(mxa, 16));
      mxa = fmaxf(mxa, __shfl_xor(mxa, 32));
      mxb = fmaxf(mxb, __shfl_xor(mxb, 16));
      mxb = fmaxf(mxb, __shfl_xor(mxb, 32));

      bool need = (mxa > ma + 8.f) || (mxb > mb + 8.f);
      if (__any(need)) {
        float mna = fmaxf(ma, mxa), mnb = fmaxf(mb, mxb);
        float aown = __expf(ma - mna), bown = __expf(mb - mnb);
        la *= aown;
        lb *= bown;
        ma = mna;
        mb = mnb;
        float alfa[4], alfb[4];
#pragma unroll
        for (int r = 0; r < 4; ++r) {
          alfa[r] = __shfl(aown, (lane & 48) | (g * 4 + r));
          alfb[r] = __shfl(bown, (lane & 48) | (g * 4 + r));
        }
#pragma unroll
        for (int n = 0; n < 8; ++n) {
          f32x4 ta = oa[n], tb = ob[n];
          ta[0] *= alfa[0]; ta[1] *= alfa[1]; ta[2] *= alfa[2]; ta[3] *= alfa[3];
          tb[0] *= alfb[0]; tb[1] *= alfb[1]; tb[2] *= alfb[2]; tb[3] *= alfb[3];
          oa[n] = ta; ob[n] = tb;
        }
      }

      float pea[4][4], peb[4][4];
#pragma unroll
      for (int n = 0; n < 4; ++n)
#pragma unroll
        for (int r = 0; r < 4; ++r) {
          pea[n][r] = __expf(sa[n][r] - ma);
          peb[n][r] = __expf(sb[n][r] - mb);
        }
      {
        float lsa = 0.f, lsb = 0.f;
#pragma unroll
        for (int n = 0; n < 4; ++n)
#pragma unroll
          for (int r = 0; r < 4; ++r) { lsa += pea[n][r]; lsb += peb[n][r]; }
        la += lsa;
        lb += lsb;
      }

      half8 paa[2], pab[2];
      {
        unsigned loa[4], hia[4], lob[4], hib[4];
#pragma unroll
        for (int n = 0; n < 4; ++n) {
          loa[n] = __builtin_bit_cast(unsigned, __builtin_amdgcn_cvt_pkrtz(pea[n][0], pea[n][1]));
          hia[n] = __builtin_bit_cast(unsigned, __builtin_amdgcn_cvt_pkrtz(pea[n][2], pea[n][3]));
          lob[n] = __builtin_bit_cast(unsigned, __builtin_amdgcn_cvt_pkrtz(peb[n][0], peb[n][1]));
          hib[n] = __builtin_bit_cast(unsigned, __builtin_amdgcn_cvt_pkrtz(peb[n][2], peb[n][3]));
        }
#pragma unroll
        for (int ks = 0; ks < 2; ++ks) {
          unsigned al = loa[ks * 2], bl = loa[ks * 2 + 1];
          unsigned ah = hia[ks * 2], bh = hia[ks * 2 + 1];
          asm("v_permlane32_swap_b32 %0, %1" : "+v"(al), "+v"(bl));
          asm("v_permlane16_swap_b32 %0, %1" : "+v"(al), "+v"(bl));
          asm("v_permlane32_swap_b32 %0, %1" : "+v"(ah), "+v"(bh));
          asm("v_permlane16_swap_b32 %0, %1" : "+v"(ah), "+v"(bh));
          u32x4 w; w[0] = al; w[1] = ah; w[2] = bl; w[3] = bh;
          paa[ks] = __builtin_bit_cast(half8, w);
          unsigned al2 = lob[ks * 2], bl2 = lob[ks * 2 + 1];
          unsigned ah2 = hib[ks * 2], bh2 = hib[ks * 2 + 1];
          asm("v_permlane32_swap_b32 %0, %1" : "+v"(al2), "+v"(bl2));
          asm("v_permlane16_swap_b32 %0, %1" : "+v"(al2), "+v"(bl2));
          asm("v_permlane32_swap_b32 %0, %1" : "+v"(ah2), "+v"(bh2));
          asm("v_permlane16_swap_b32 %0, %1" : "+v"(ah2), "+v"(bh2));
          u32x4 w2; w2[0] = al2; w2[1] = ah2; w2[2] = bl2; w2[3] = bh2;
          pab[ks] = __builtin_bit_cast(half8, w2);
        }
      }

      __builtin_amdgcn_s_setprio(1);
#pragma unroll
      for (int n = 0; n < 8; ++n) {
        int d = n * 16 + (lane & 15);
#pragma unroll
        for (int ks = 0; ks < 2; ++ks) {
          half8 vf = *reinterpret_cast<const half8*>(
              Vs[cur] + d * 128 + (((ks * 4 + g) ^ (d & 7)) * 16));
          oa[n] = __builtin_amdgcn_mfma_f32_16x16x32_f16(paa[ks], vf, oa[n], 0, 0, 0);
          ob[n] = __builtin_amdgcn_mfma_f32_16x16x32_f16(pab[ks], vf, ob[n], 0, 0, 0);
        }
      }
      __builtin_amdgcn_s_setprio(0);
    }
    __syncthreads();
  }

  // epilogue: collapse deferred l partials, then rcp + multiply
  la += __shfl_xor(la, 16);
  la += __shfl_xor(la, 32);
  lb += __shfl_xor(lb, 16);
  lb += __shfl_xor(lb, 32);
  float lra[4], lrb[4];
#pragma unroll
  for (int r = 0; r < 4; ++r) {
    lra[r] = __builtin_amdgcn_rcpf(__shfl(la, (lane & 48) | (g * 4 + r)));
    lrb[r] = __builtin_amdgcn_rcpf(__shfl(lb, (lane & 48) | (g * 4 + r)));
  }
#pragma unroll
  for (int n = 0; n < 8; ++n) {
    int d = colbase + n * 16 + (lane & 15);
#pragma unroll
    for (int r = 0; r < 4; ++r) {
      int rowa = q0 + wave * 32 + (g << 2) + r;
      O[(sbase + rowa) * 2048 + d] = (_Float16)(oa[n][r] * lra[r]);
      O[(sbase + rowa + 16) * 2048 + d] = (_Float16)(ob[n][r] * lrb[r]);
    }
  }
}

extern "C" void kernel_launch(void* const* d_in, const int* in_sizes, int n_in,
                              void* d_out, int out_size, void* d_ws, size_t ws_size,
                              hipStream_t stream) {
  const float* x     = (const float*)d_in[0];
  const float* Wq_d  = (const float*)d_in[1];
  const float* Wkv_d = (const float*)d_in[2];
  const float* Wq_u  = (const float*)d_in[3];
  const float* Wk_u  = (const float*)d_in[4];
  const float* Wv_u  = (const float*)d_in[5];
  const float* Wo    = (const float*)d_in[6];
  char* ws = (char*)d_ws;
  _Float16* xb  = (_Float16*)(ws);              // [4096][2048] (reused as ao)
  _Float16* wdT = (_Float16*)(ws + 16777216);   // [1024][2048]
  _Float16* wuT = (_Float16*)(ws + 20971520);   // 3x [2048][512]
  _Float16* woT = (_Float16*)(ws + 27262976);   // [2048][2048]
  _Float16* lat = (_Float16*)(ws + 35651584);   // [4096][1024]
  _Float16* qb  = (_Float16*)(ws + 44040192);   // [4096][2048]
  _Float16* kb  = (_Float16*)(ws + 60817408);   // [4096][2048]
  _Float16* vT  = (_Float16*)(ws + 77594624);   // [2048 d][4096 s]
  float*    tab = (float*)(ws + 77594624);      // 1 MB trig table, head of vT region:
                                                // written by prep, read by gemm_qk,
                                                // overwritten later by the v-GEMM (after qk).
  _Float16* ao  = xb;

  // fused conv (vectorized) + all weight transposes + trig table (one dispatch)
  prep<<<13824, 256, 0, stream>>>(x, xb, Wq_d, Wkv_d, Wq_u, Wk_u, Wv_u, Wo, wdT, wuT, woT, tab);

  // lat = x @ [Wq_d | Wkv_d]
  gemm_bt<0><<<dim3(8, 32), 256, 0, stream>>>(xb, 2048, wdT, 2048, lat, 1024, 2048, nullptr);

  // q = RoPE(lat_q @ Wq_u) ; k = RoPE(lat_kv @ Wk_u)  -- merged, one dispatch (reads tab)
  gemm_qk<<<1024, 256, 0, stream>>>(lat, wuT, qb, kb, tab);
  // vT[d][s] = Wv_u^T @ lat_kv^T  (overwrites the tab region — tab is dead now)
  gemm_bt<0><<<dim3(32, 16), 256, 0, stream>>>(wuT + 2 * 2048 * 512, 512, lat + 512, 1024, vT, 4096, 512, nullptr);

  attn_fused<<<dim3(16, 16, 2), 256, 0, stream>>>(qb, kb, vT, ao);

  gemm_bt<1><<<dim3(16, 32), 256, 0, stream>>>(ao, 2048, woT, 2048, d_out, 2048, 2048, nullptr);
}